// Round 1
// baseline (1811.054 us; speedup 1.0000x reference)
//
#include <hip/hip_runtime.h>

// Problem constants: B=8, C=192, H=W=128, NH=6, HD=32, WS=8, N=64 tokens/window
#define SCALEQ 0.17677669529663687f   // 32^-0.5

__device__ __forceinline__ float b2f(unsigned short u) {
    return __uint_as_float(((unsigned int)u) << 16);
}
__device__ __forceinline__ unsigned short f2b(float f) {
    unsigned int u = __float_as_uint(f);
    u += 0x7fffu + ((u >> 16) & 1u);      // round-to-nearest-even
    return (unsigned short)(u >> 16);
}

// LDS byte offsets (all 16B aligned). Unions by lifetime:
//   [0]      xs  [192][64] bf16 (24576)  phases 1-2   | o [64][196] bf16 (25088) phases 3-5
//   [25088]  q   [64][196] bf16 (25088)  phases 2-3   | y [192][64] bf16 (24576) phases 5-7
//   [50176]  k   [64][196] bf16 (25088)  phases 2-3
//   [75264]  v   [64][196] bf16 (25088)  phases 2-5
//   [100352] Ws  [16][196] f32  (12544)  phases 2,7
//   [112896] bias_t [225][6] f32 (5400)  phases 0,5
#define OFF_O   0
#define OFF_Q   25088
#define OFF_K   50176
#define OFF_V   75264
#define OFF_WS  100352
#define OFF_BT  112896
#define LDS_BYTES 118296

__global__ __launch_bounds__(256)
void fused_win_attn(const float* __restrict__ x,
                    const float* __restrict__ Vw,  const float* __restrict__ Vb,
                    const float* __restrict__ QKw, const float* __restrict__ QKb,
                    const float* __restrict__ Pw,  const float* __restrict__ Pb,
                    const float* __restrict__ Mw1, const float* __restrict__ Mb1,
                    const float* __restrict__ Mw2, const float* __restrict__ Mb2,
                    float* __restrict__ out)
{
    extern __shared__ char smem[];
    unsigned short* xs  = (unsigned short*)(smem + OFF_O);
    unsigned short* o_s = (unsigned short*)(smem + OFF_O);
    unsigned short* q_s = (unsigned short*)(smem + OFF_Q);
    unsigned short* y_s = (unsigned short*)(smem + OFF_Q);
    unsigned short* k_s = (unsigned short*)(smem + OFF_K);
    unsigned short* v_s = (unsigned short*)(smem + OFF_V);
    float* Ws     = (float*)(smem + OFF_WS);
    float* bias_t = (float*)(smem + OFF_BT);

    const int t   = threadIdx.x;
    const int wid = blockIdx.x;
    const int b   = wid >> 8;          // 256 windows per image (16x16)
    const int wy  = (wid >> 4) & 15;
    const int wx  = wid & 15;
    const int y0  = wy * 8, x0 = wx * 8;

    // ---- Phase 0: rel-pos bias table. bias depends only on (dy,dx) in [-7,7]^2 ----
    if (t < 225) {
        int dyi = t / 15, dxi = t % 15;
        float dy = (float)(dyi - 7), dx = (float)(dxi - 7);
        float f0 = copysignf(log1pf(fabsf(dy)), dy);
        float f1 = copysignf(log1pf(fabsf(dx)), dx);
        float a0 = Mb2[0], a1 = Mb2[1], a2 = Mb2[2],
              a3 = Mb2[3], a4 = Mb2[4], a5 = Mb2[5];
        for (int u = 0; u < 256; ++u) {
            float hv = fmaxf(f0 * Mw1[u] + f1 * Mw1[256 + u] + Mb1[u], 0.0f);
            const float* w2 = Mw2 + u * 6;
            a0 = fmaf(hv, w2[0], a0); a1 = fmaf(hv, w2[1], a1);
            a2 = fmaf(hv, w2[2], a2); a3 = fmaf(hv, w2[3], a3);
            a4 = fmaf(hv, w2[4], a4); a5 = fmaf(hv, w2[5], a5);
        }
        float* bt = bias_t + t * 6;
        bt[0] = a0; bt[1] = a1; bt[2] = a2; bt[3] = a3; bt[4] = a4; bt[5] = a5;
    }

    // ---- Phase 1: load x tile (64 pixels x 192 ch) -> xs[c][n] bf16 ----
    {
        const float* xb = x + (size_t)b * 192 * 16384;
        #pragma unroll
        for (int i = 0; i < 12; ++i) {
            int idx = t + 256 * i;              // 3072 float4 loads
            int c = idx >> 4, sub = idx & 15;
            int r = sub >> 1, hf = sub & 1;
            float4 v4 = *(const float4*)(xb + c * 16384 + (y0 + r) * 128 + x0 + hf * 4);
            ushort4 s4;
            s4.x = f2b(v4.x); s4.y = f2b(v4.y); s4.z = f2b(v4.z); s4.w = f2b(v4.w);
            *(ushort4*)(xs + c * 64 + r * 8 + hf * 4) = s4;
        }
    }

    const int tm = t >> 4, tn = t & 15;
    const int nb = tm * 4, ob = tn * 12;

    // ---- Phase 2: qkv GEMM  (M=64 tokens, N=576 out-ch, K=192), fp32 accum ----
    for (int pass = 0; pass < 3; ++pass) {
        const int obase = pass * 192;
        float acc[4][12];
        #pragma unroll
        for (int i = 0; i < 4; ++i)
            #pragma unroll
            for (int j = 0; j < 12; ++j) acc[i][j] = 0.0f;

        for (int k0 = 0; k0 < 192; k0 += 16) {
            #pragma unroll
            for (int i = 0; i < 12; ++i) {      // stage Ws[kk][o] fp32
                int idx = t + 256 * i;
                int o = idx >> 4, kk = idx & 15;
                int row = obase + o;
                const float* wr = (row < 384) ? (QKw + row * 192) : (Vw + (row - 384) * 192);
                Ws[kk * 196 + o] = wr[k0 + kk];
            }
            __syncthreads();
            #pragma unroll 4
            for (int kk = 0; kk < 16; ++kk) {
                ushort4 a4 = *(const ushort4*)(xs + (k0 + kk) * 64 + nb);
                float av0 = b2f(a4.x), av1 = b2f(a4.y), av2 = b2f(a4.z), av3 = b2f(a4.w);
                const float* wrow = Ws + kk * 196 + ob;
                float4 bq0 = *(const float4*)(wrow);
                float4 bq1 = *(const float4*)(wrow + 4);
                float4 bq2 = *(const float4*)(wrow + 8);
                float bb[12] = {bq0.x, bq0.y, bq0.z, bq0.w,
                                bq1.x, bq1.y, bq1.z, bq1.w,
                                bq2.x, bq2.y, bq2.z, bq2.w};
                #pragma unroll
                for (int j = 0; j < 12; ++j) {
                    acc[0][j] = fmaf(av0, bb[j], acc[0][j]);
                    acc[1][j] = fmaf(av1, bb[j], acc[1][j]);
                    acc[2][j] = fmaf(av2, bb[j], acc[2][j]);
                    acc[3][j] = fmaf(av3, bb[j], acc[3][j]);
                }
            }
            __syncthreads();
        }
        // write q (scaled), k, v as bf16 [n][196]
        #pragma unroll
        for (int j = 0; j < 12; ++j) {
            int row = obase + ob + j;
            float bv = (row < 384) ? QKb[row] : Vb[row - 384];
            #pragma unroll
            for (int i = 0; i < 4; ++i) {
                float val = acc[i][j] + bv;
                int n = nb + i;
                if (row < 192)      q_s[n * 196 + row]         = f2b(val * SCALEQ);
                else if (row < 384) k_s[n * 196 + (row - 192)] = f2b(val);
                else                v_s[n * 196 + (row - 384)] = f2b(val);
            }
        }
    }
    __syncthreads();

    // ---- Phase 3: 8x8 circular convolution o[n][c] = sum_{n'} q[n'][c]*k[(n-n') mod][c] ----
    {
        const int n = t & 63, g = t >> 6;
        const int c0 = g * 48;
        const int rn = n >> 3, cn = n & 7;
        float acc[48];
        #pragma unroll
        for (int j = 0; j < 48; ++j) acc[j] = 0.0f;
        for (int np = 0; np < 64; ++np) {
            int m = (((rn - (np >> 3)) & 7) << 3) | ((cn - (np & 7)) & 7);
            const unsigned short* qrow = q_s + np * 196 + c0;
            const unsigned short* krow = k_s + m * 196 + c0;
            #pragma unroll
            for (int j = 0; j < 12; ++j) {
                ushort4 qa = *(const ushort4*)(qrow + 4 * j);
                ushort4 ka = *(const ushort4*)(krow + 4 * j);
                acc[4*j+0] = fmaf(b2f(qa.x), b2f(ka.x), acc[4*j+0]);
                acc[4*j+1] = fmaf(b2f(qa.y), b2f(ka.y), acc[4*j+1]);
                acc[4*j+2] = fmaf(b2f(qa.z), b2f(ka.z), acc[4*j+2]);
                acc[4*j+3] = fmaf(b2f(qa.w), b2f(ka.w), acc[4*j+3]);
            }
        }
        // o region unions with xs (dead since phase 2); q/k regions untouched here
        #pragma unroll
        for (int j = 0; j < 24; ++j) {
            unsigned int pk = (unsigned int)f2b(acc[2*j]) | ((unsigned int)f2b(acc[2*j+1]) << 16);
            *(unsigned int*)(o_s + n * 196 + c0 + 2 * j) = pk;
        }
    }
    __syncthreads();

    // ---- Phase 5: per-head attention: S = o.v^T + bias, softmax, y = P.v ----
    {
        const int n = t >> 2, mc = t & 3;            // 4 lanes per query row (same wave)
        const int rn = n >> 3, cn = n & 7;
        for (int h = 0; h < 6; ++h) {
            const int hc = h * 32;
            float ov[32];
            #pragma unroll
            for (int j = 0; j < 8; ++j) {
                ushort4 oa = *(const ushort4*)(o_s + n * 196 + hc + 4 * j);
                ov[4*j+0] = b2f(oa.x); ov[4*j+1] = b2f(oa.y);
                ov[4*j+2] = b2f(oa.z); ov[4*j+3] = b2f(oa.w);
            }
            float P[16];
            float mx = -1e30f;
            #pragma unroll
            for (int i = 0; i < 16; ++i) {
                int m = mc * 16 + i;
                int dy = rn - (m >> 3) + 7, dx = cn - (m & 7) + 7;
                float s = bias_t[(dy * 15 + dx) * 6 + h];
                const unsigned short* vrow = v_s + m * 196 + hc;
                #pragma unroll
                for (int j = 0; j < 8; ++j) {
                    ushort4 va = *(const ushort4*)(vrow + 4 * j);
                    s = fmaf(ov[4*j+0], b2f(va.x), s);
                    s = fmaf(ov[4*j+1], b2f(va.y), s);
                    s = fmaf(ov[4*j+2], b2f(va.z), s);
                    s = fmaf(ov[4*j+3], b2f(va.w), s);
                }
                P[i] = s;
                mx = fmaxf(mx, s);
            }
            mx = fmaxf(mx, __shfl_xor(mx, 1));
            mx = fmaxf(mx, __shfl_xor(mx, 2));
            float sum = 0.0f;
            #pragma unroll
            for (int i = 0; i < 16; ++i) { P[i] = __expf(P[i] - mx); sum += P[i]; }
            sum += __shfl_xor(sum, 1);
            sum += __shfl_xor(sum, 2);
            float inv = 1.0f / sum;
            float ya[32];
            #pragma unroll
            for (int d = 0; d < 32; ++d) ya[d] = 0.0f;
            #pragma unroll
            for (int i = 0; i < 16; ++i) {
                float p = P[i];
                const unsigned short* vrow = v_s + (mc * 16 + i) * 196 + hc;
                #pragma unroll
                for (int j = 0; j < 8; ++j) {
                    ushort4 va = *(const ushort4*)(vrow + 4 * j);
                    ya[4*j+0] = fmaf(p, b2f(va.x), ya[4*j+0]);
                    ya[4*j+1] = fmaf(p, b2f(va.y), ya[4*j+1]);
                    ya[4*j+2] = fmaf(p, b2f(va.z), ya[4*j+2]);
                    ya[4*j+3] = fmaf(p, b2f(va.w), ya[4*j+3]);
                }
            }
            #pragma unroll
            for (int d = 0; d < 32; ++d) {
                ya[d] += __shfl_xor(ya[d], 1);
                ya[d] += __shfl_xor(ya[d], 2);
            }
            // y layout [c][n] for proj a-vector reads; y unions with q (dead)
            #pragma unroll
            for (int j = 0; j < 8; ++j) {
                int c = hc + mc * 8 + j;
                y_s[c * 64 + n] = f2b(ya[mc * 8 + j] * inv);
            }
        }
    }
    __syncthreads();

    // ---- Phase 7: proj GEMM (M=64, N=192, K=192) + write out ----
    {
        float acc[4][12];
        #pragma unroll
        for (int i = 0; i < 4; ++i)
            #pragma unroll
            for (int j = 0; j < 12; ++j) acc[i][j] = 0.0f;
        for (int k0 = 0; k0 < 192; k0 += 16) {
            #pragma unroll
            for (int i = 0; i < 12; ++i) {
                int idx = t + 256 * i;
                int o = idx >> 4, kk = idx & 15;
                Ws[kk * 196 + o] = Pw[o * 192 + k0 + kk];
            }
            __syncthreads();
            #pragma unroll 4
            for (int kk = 0; kk < 16; ++kk) {
                ushort4 a4 = *(const ushort4*)(y_s + (k0 + kk) * 64 + nb);
                float av0 = b2f(a4.x), av1 = b2f(a4.y), av2 = b2f(a4.z), av3 = b2f(a4.w);
                const float* wrow = Ws + kk * 196 + ob;
                float4 bq0 = *(const float4*)(wrow);
                float4 bq1 = *(const float4*)(wrow + 4);
                float4 bq2 = *(const float4*)(wrow + 8);
                float bb[12] = {bq0.x, bq0.y, bq0.z, bq0.w,
                                bq1.x, bq1.y, bq1.z, bq1.w,
                                bq2.x, bq2.y, bq2.z, bq2.w};
                #pragma unroll
                for (int j = 0; j < 12; ++j) {
                    acc[0][j] = fmaf(av0, bb[j], acc[0][j]);
                    acc[1][j] = fmaf(av1, bb[j], acc[1][j]);
                    acc[2][j] = fmaf(av2, bb[j], acc[2][j]);
                    acc[3][j] = fmaf(av3, bb[j], acc[3][j]);
                }
            }
            __syncthreads();
        }
        // thread's 4 tokens are 4 consecutive x-positions in one row -> float4 stores
        const int r = tm >> 1, cc0 = (tm & 1) * 4;
        float* obp = out + (size_t)(b * 192) * 16384 + (size_t)(y0 + r) * 128 + x0 + cc0;
        #pragma unroll
        for (int j = 0; j < 12; ++j) {
            int oc = ob + j;
            float pb = Pb[oc];
            float4 v4;
            v4.x = acc[0][j] + pb; v4.y = acc[1][j] + pb;
            v4.z = acc[2][j] + pb; v4.w = acc[3][j] + pb;
            *(float4*)(obp + (size_t)oc * 16384) = v4;
        }
    }
}

extern "C" void kernel_launch(void* const* d_in, const int* in_sizes, int n_in,
                              void* d_out, int out_size, void* d_ws, size_t ws_size,
                              hipStream_t stream) {
    const float* x   = (const float*)d_in[0];
    const float* Vw  = (const float*)d_in[1];
    const float* Vb  = (const float*)d_in[2];
    const float* QKw = (const float*)d_in[3];
    const float* QKb = (const float*)d_in[4];
    const float* Pw  = (const float*)d_in[5];
    const float* Pb  = (const float*)d_in[6];
    const float* Mw1 = (const float*)d_in[7];
    const float* Mb1 = (const float*)d_in[8];
    const float* Mw2 = (const float*)d_in[9];
    const float* Mb2 = (const float*)d_in[10];
    float* outp = (float*)d_out;
    (void)hipFuncSetAttribute((const void*)fused_win_attn,
                              hipFuncAttributeMaxDynamicSharedMemorySize, LDS_BYTES);
    fused_win_attn<<<dim3(2048), dim3(256), LDS_BYTES, stream>>>(
        x, Vw, Vb, QKw, QKb, Pw, Pb, Mw1, Mb1, Mw2, Mb2, outp);
}

// Round 3
// 542.214 us; speedup vs baseline: 3.3401x; 3.3401x over previous
//
#include <hip/hip_runtime.h>

// B=8, C=192, H=W=128, NH=6, HD=32, WS=8, N=64 tokens/window. 2048 windows.
#define SCALEQ 0.17677669529663687f   // 32^-0.5

typedef __bf16 bf16x8 __attribute__((ext_vector_type(8)));
typedef float f32x4 __attribute__((ext_vector_type(4)));

__device__ __forceinline__ float bflo(unsigned int u) { return __uint_as_float(u << 16); }
__device__ __forceinline__ float bfhi(unsigned int u) { return __uint_as_float(u & 0xffff0000u); }
__device__ __forceinline__ unsigned short f2b(float f) {
    unsigned int u = __float_as_uint(f);
    u += 0x7fffu + ((u >> 16) & 1u);      // RNE
    return (unsigned short)(u >> 16);
}

// LDS map (all swizzled: byte ^= (row&7)<<4; strides: 384B for [64][192], 128B for [*][64])
//  BUF0   0      xs[64][192] (P1-P2) | o[64][192] (P3-P4) | y[64][192] (P5-P6)
//  QOFF   24576  q[64][192] (P2-P3)  | P: 6 heads x [64][64] bf16, 8KB/head (P4-P5)
//  KOFF   49152  k[64][192] (P2-P3)  | (P heads 3..5)
//  VOFF   73728  v_n[64][192] (P2-P4)
//  VTOFF  98304  v_t[192][64] (P2-P5)
//  BTOFF  122880 bias table 225*6 f32 (5400B)
#define BUF0   0
#define QOFF   24576
#define KOFF   49152
#define POFF   24576
#define VOFF   73728
#define VTOFF  98304
#define BTOFF  122880
#define LDS_BYTES 128280

__device__ __forceinline__ bf16x8 ldsf(const char* p) {
    uint4 u = *(const uint4*)p;
    return __builtin_bit_cast(bf16x8, u);
}
__device__ __forceinline__ bf16x8 wfrag(const float* p) {
    float4 a = *(const float4*)p;
    float4 c = *(const float4*)(p + 4);
    bf16x8 r;
    r[0] = (__bf16)a.x; r[1] = (__bf16)a.y; r[2] = (__bf16)a.z; r[3] = (__bf16)a.w;
    r[4] = (__bf16)c.x; r[5] = (__bf16)c.y; r[6] = (__bf16)c.z; r[7] = (__bf16)c.w;
    return r;
}

// ---- precompute kernel: rel-pos bias MLP table (225 x 6) -> d_ws ----
__global__ void bias_table_kernel(const float* __restrict__ Mw1, const float* __restrict__ Mb1,
                                  const float* __restrict__ Mw2, const float* __restrict__ Mb2,
                                  float* __restrict__ bias_out) {
    int t = blockIdx.x * 64 + threadIdx.x;
    if (t >= 225) return;
    int dyi = t / 15, dxi = t % 15;
    float dy = (float)(dyi - 7), dx = (float)(dxi - 7);
    float f0 = copysignf(log1pf(fabsf(dy)), dy);
    float f1 = copysignf(log1pf(fabsf(dx)), dx);
    float a0 = Mb2[0], a1 = Mb2[1], a2 = Mb2[2], a3 = Mb2[3], a4 = Mb2[4], a5 = Mb2[5];
    for (int u = 0; u < 256; ++u) {
        float hv = fmaxf(f0 * Mw1[u] + f1 * Mw1[256 + u] + Mb1[u], 0.0f);
        const float* w2 = Mw2 + u * 6;
        a0 = fmaf(hv, w2[0], a0); a1 = fmaf(hv, w2[1], a1);
        a2 = fmaf(hv, w2[2], a2); a3 = fmaf(hv, w2[3], a3);
        a4 = fmaf(hv, w2[4], a4); a5 = fmaf(hv, w2[5], a5);
    }
    float* bt = bias_out + t * 6;
    bt[0] = a0; bt[1] = a1; bt[2] = a2; bt[3] = a3; bt[4] = a4; bt[5] = a5;
}

__global__ __launch_bounds__(256)
void fused_win_attn(const float* __restrict__ x,
                    const float* __restrict__ Vw,  const float* __restrict__ Vb,
                    const float* __restrict__ QKw, const float* __restrict__ QKb,
                    const float* __restrict__ Pw,  const float* __restrict__ Pb,
                    const float* __restrict__ bias_g,
                    float* __restrict__ out)
{
    extern __shared__ char smem[];
    const int t   = threadIdx.x;
    const int w   = t >> 6;           // wave 0..3
    const int l15 = t & 15;
    const int l4  = (t >> 4) & 3;     // (lane>>4)

    const int wid = blockIdx.x;
    const int b   = wid >> 8;
    const int wy  = (wid >> 4) & 15;
    const int wx  = wid & 15;
    const int y0  = wy * 8, x0 = wx * 8;

    const f32x4 zz = {0.0f, 0.0f, 0.0f, 0.0f};

    // ---- P0: bias table global -> LDS ----
    {
        float* bt = (float*)(smem + BTOFF);
        for (int i = t; i < 1350; i += 256) bt[i] = bias_g[i];
    }

    // ---- P1: load x window -> xs[tok][ch] bf16 swizzled ----
    {
        const float* xb = x + (size_t)b * 192 * 16384;
        #pragma unroll
        for (int i = 0; i < 12; ++i) {
            int idx = t + 256 * i;
            int c = idx >> 4, sub = idx & 15;
            int r = sub >> 1, hf = sub & 1;
            float4 v4 = *(const float4*)(xb + c * 16384 + (y0 + r) * 128 + x0 + hf * 4);
            int n0 = r * 8 + hf * 4;
            unsigned short sv[4] = {f2b(v4.x), f2b(v4.y), f2b(v4.z), f2b(v4.w)};
            #pragma unroll
            for (int e = 0; e < 4; ++e) {
                int n = n0 + e;
                *(unsigned short*)(smem + BUF0 + ((n * 384 + c * 2) ^ ((n & 7) << 4))) = sv[e];
            }
        }
    }
    __syncthreads();

    // ---- P2: qkv GEMM via MFMA. wave w owns out-cols [144w, 144w+144) ----
    for (int chunk = 0; chunk < 3; ++chunk) {
        f32x4 acc[3][4];
        #pragma unroll
        for (int j = 0; j < 3; ++j)
            #pragma unroll
            for (int mt = 0; mt < 4; ++mt) acc[j][mt] = zz;

        #pragma unroll
        for (int ks = 0; ks < 6; ++ks) {
            bf16x8 afr[4];
            #pragma unroll
            for (int mt = 0; mt < 4; ++mt) {
                int row = mt * 16 + l15;
                afr[mt] = ldsf(smem + BUF0 + ((row * 384 + ks * 64 + l4 * 16) ^ ((row & 7) << 4)));
            }
            bf16x8 bfr[3];
            #pragma unroll
            for (int j = 0; j < 3; ++j) {
                int ob = w * 144 + chunk * 48 + j * 16;
                const float* wrow = (ob < 384) ? (QKw + (size_t)(ob + l15) * 192)
                                               : (Vw + (size_t)(ob - 384 + l15) * 192);
                bfr[j] = wfrag(wrow + ks * 32 + l4 * 8);
            }
            #pragma unroll
            for (int j = 0; j < 3; ++j)
                #pragma unroll
                for (int mt = 0; mt < 4; ++mt)
                    acc[j][mt] = __builtin_amdgcn_mfma_f32_16x16x32_bf16(afr[mt], bfr[j], acc[j][mt], 0, 0, 0);
        }
        // epilogue: +bias, scale q, write q/k/v (v also transposed)
        #pragma unroll
        for (int j = 0; j < 3; ++j) {
            int ob  = w * 144 + chunk * 48 + j * 16;
            int och = ob + l15;
            float bv = (ob < 384) ? QKb[och] : Vb[och - 384];
            #pragma unroll
            for (int mt = 0; mt < 4; ++mt) {
                #pragma unroll
                for (int rr = 0; rr < 4; ++rr) {
                    float val = acc[j][mt][rr] + bv;
                    int tok = mt * 16 + l4 * 4 + rr;
                    if (ob < 192) {
                        *(unsigned short*)(smem + QOFF + ((tok * 384 + och * 2) ^ ((tok & 7) << 4))) = f2b(val * SCALEQ);
                    } else if (ob < 384) {
                        int ch = och - 192;
                        *(unsigned short*)(smem + KOFF + ((tok * 384 + ch * 2) ^ ((tok & 7) << 4))) = f2b(val);
                    } else {
                        int ch = och - 384;
                        unsigned short hv = f2b(val);
                        *(unsigned short*)(smem + VOFF  + ((tok * 384 + ch * 2) ^ ((tok & 7) << 4))) = hv;
                        *(unsigned short*)(smem + VTOFF + ((ch * 128 + tok * 2) ^ ((ch & 7) << 4))) = hv;
                    }
                }
            }
        }
    }
    __syncthreads();

    // ---- P3: 8x8 circular conv, register-blocked. 192 threads x 2 channel passes ----
    // FIX(round 2): round 1 covered only channels 0..95 (24 chunks x 4ch). Outer cp loop
    // adds channels 96..191: coverage = 8 rows x (24 chunks x 2 passes x 4 ch) = 192. 
    if (t < 192) {
        const int rn = t / 24, cc = t % 24;
        #pragma unroll
        for (int cp = 0; cp < 2; ++cp) {
            const int c0b = cc * 8 + cp * 192;    // byte offset of 4-ch chunk
            float acc[8][4];
            #pragma unroll
            for (int cn = 0; cn < 8; ++cn)
                #pragma unroll
                for (int c = 0; c < 4; ++c) acc[cn][c] = 0.0f;

            #pragma unroll
            for (int kh = 0; kh < 2; ++kh) {
                unsigned int klo[32], khi[32];
                #pragma unroll
                for (int m = 0; m < 32; ++m) {
                    int row = kh * 32 + m;
                    uint2 kv = *(const uint2*)(smem + KOFF + ((row * 384 + c0b) ^ ((row & 7) << 4)));
                    klo[m] = kv.x; khi[m] = kv.y;
                }
                #pragma unroll
                for (int mrl = 0; mrl < 4; ++mrl) {
                    const int mr = kh * 4 + mrl;
                    float kf[8][4];
                    #pragma unroll
                    for (int mc = 0; mc < 8; ++mc) {
                        int m = mrl * 8 + mc;
                        kf[mc][0] = bflo(klo[m]); kf[mc][1] = bfhi(klo[m]);
                        kf[mc][2] = bflo(khi[m]); kf[mc][3] = bfhi(khi[m]);
                    }
                    const int npr = (rn - mr) & 7;
                    #pragma unroll
                    for (int npc = 0; npc < 8; ++npc) {
                        int np = npr * 8 + npc;
                        uint2 qv = *(const uint2*)(smem + QOFF + ((np * 384 + c0b) ^ ((np & 7) << 4)));
                        float qf[4] = {bflo(qv.x), bfhi(qv.x), bflo(qv.y), bfhi(qv.y)};
                        #pragma unroll
                        for (int mc = 0; mc < 8; ++mc) {
                            int cn = (npc + mc) & 7;
                            acc[cn][0] = fmaf(qf[0], kf[mc][0], acc[cn][0]);
                            acc[cn][1] = fmaf(qf[1], kf[mc][1], acc[cn][1]);
                            acc[cn][2] = fmaf(qf[2], kf[mc][2], acc[cn][2]);
                            acc[cn][3] = fmaf(qf[3], kf[mc][3], acc[cn][3]);
                        }
                    }
                }
            }
            #pragma unroll
            for (int cn = 0; cn < 8; ++cn) {
                int n = rn * 8 + cn;
                uint2 pk;
                pk.x = (unsigned int)f2b(acc[cn][0]) | ((unsigned int)f2b(acc[cn][1]) << 16);
                pk.y = (unsigned int)f2b(acc[cn][2]) | ((unsigned int)f2b(acc[cn][3]) << 16);
                *(uint2*)(smem + BUF0 + ((n * 384 + c0b) ^ ((n & 7) << 4))) = pk;
            }
        }
    }
    __syncthreads();

    // ---- P4: S = o.v^T + bias, softmax, P -> LDS. 24 units (h, mt), 6 per wave ----
    {
        const float* bt = (const float*)(smem + BTOFF);
        for (int i = 0; i < 6; ++i) {
            int u = w * 6 + i;
            int h = u >> 2, mt = u & 3;
            int arow = mt * 16 + l15;
            bf16x8 afr = ldsf(smem + BUF0 + ((arow * 384 + h * 64 + l4 * 16) ^ ((arow & 7) << 4)));
            f32x4 acc[4];
            #pragma unroll
            for (int nt = 0; nt < 4; ++nt) {
                int brow = nt * 16 + l15;
                bf16x8 bfr = ldsf(smem + VOFF + ((brow * 384 + h * 64 + l4 * 16) ^ ((brow & 7) << 4)));
                acc[nt] = __builtin_amdgcn_mfma_f32_16x16x32_bf16(afr, bfr, zz, 0, 0, 0);
            }
            float s[4][4];
            #pragma unroll
            for (int nt = 0; nt < 4; ++nt) {
                int m = nt * 16 + l15;
                int myr = m >> 3, myc = m & 7;
                #pragma unroll
                for (int rr = 0; rr < 4; ++rr) {
                    int n = mt * 16 + l4 * 4 + rr;
                    int dy = (n >> 3) - myr + 7, dx = (n & 7) - myc + 7;
                    s[nt][rr] = acc[nt][rr] + bt[(dy * 15 + dx) * 6 + h];
                }
            }
            float inv[4];
            #pragma unroll
            for (int rr = 0; rr < 4; ++rr) {
                float m0 = fmaxf(fmaxf(s[0][rr], s[1][rr]), fmaxf(s[2][rr], s[3][rr]));
                m0 = fmaxf(m0, __shfl_xor(m0, 1));
                m0 = fmaxf(m0, __shfl_xor(m0, 2));
                m0 = fmaxf(m0, __shfl_xor(m0, 4));
                m0 = fmaxf(m0, __shfl_xor(m0, 8));
                float sm = 0.0f;
                #pragma unroll
                for (int nt = 0; nt < 4; ++nt) {
                    float p = __expf(s[nt][rr] - m0);
                    s[nt][rr] = p; sm += p;
                }
                sm += __shfl_xor(sm, 1); sm += __shfl_xor(sm, 2);
                sm += __shfl_xor(sm, 4); sm += __shfl_xor(sm, 8);
                inv[rr] = 1.0f / sm;
            }
            #pragma unroll
            for (int nt = 0; nt < 4; ++nt)
                #pragma unroll
                for (int rr = 0; rr < 4; ++rr) {
                    int n = mt * 16 + l4 * 4 + rr, m = nt * 16 + l15;
                    *(unsigned short*)(smem + POFF + h * 8192 + ((n * 128 + m * 2) ^ ((n & 7) << 4)))
                        = f2b(s[nt][rr] * inv[rr]);
                }
        }
    }
    __syncthreads();

    // ---- P5: Y = P.v  (per (h,mt) unit) -> y[tok][ch] in BUF0 ----
    {
        for (int i = 0; i < 6; ++i) {
            int u = w * 6 + i;
            int h = u >> 2, mt = u & 3;
            bf16x8 pa[2];
            #pragma unroll
            for (int ks = 0; ks < 2; ++ks) {
                int row = mt * 16 + l15;
                pa[ks] = ldsf(smem + POFF + h * 8192 + ((row * 128 + ks * 64 + l4 * 16) ^ ((row & 7) << 4)));
            }
            f32x4 acc[2];
            acc[0] = zz; acc[1] = zz;
            #pragma unroll
            for (int dt = 0; dt < 2; ++dt)
                #pragma unroll
                for (int ks = 0; ks < 2; ++ks) {
                    int ch = h * 32 + dt * 16 + l15;
                    bf16x8 bfr = ldsf(smem + VTOFF + ((ch * 128 + ks * 64 + l4 * 16) ^ ((ch & 7) << 4)));
                    acc[dt] = __builtin_amdgcn_mfma_f32_16x16x32_bf16(pa[ks], bfr, acc[dt], 0, 0, 0);
                }
            #pragma unroll
            for (int dt = 0; dt < 2; ++dt)
                #pragma unroll
                for (int rr = 0; rr < 4; ++rr) {
                    int tok = mt * 16 + l4 * 4 + rr;
                    int ch  = h * 32 + dt * 16 + l15;
                    *(unsigned short*)(smem + BUF0 + ((tok * 384 + ch * 2) ^ ((tok & 7) << 4))) = f2b(acc[dt][rr]);
                }
        }
    }
    __syncthreads();

    // ---- P6: proj, transposed: OUTt[oc][tok] = Pw . y^T. wave w: oc [48w, 48w+48) ----
    {
        f32x4 acc[3][4];
        #pragma unroll
        for (int jt = 0; jt < 3; ++jt)
            #pragma unroll
            for (int nt = 0; nt < 4; ++nt) acc[jt][nt] = zz;

        #pragma unroll
        for (int ks = 0; ks < 6; ++ks) {
            bf16x8 bfr[4];
            #pragma unroll
            for (int nt = 0; nt < 4; ++nt) {
                int tok = nt * 16 + l15;
                bfr[nt] = ldsf(smem + BUF0 + ((tok * 384 + ks * 64 + l4 * 16) ^ ((tok & 7) << 4)));
            }
            #pragma unroll
            for (int jt = 0; jt < 3; ++jt) {
                int oc = w * 48 + jt * 16 + l15;
                bf16x8 afr = wfrag(Pw + (size_t)oc * 192 + ks * 32 + l4 * 8);
                #pragma unroll
                for (int nt = 0; nt < 4; ++nt)
                    acc[jt][nt] = __builtin_amdgcn_mfma_f32_16x16x32_bf16(afr, bfr[nt], acc[jt][nt], 0, 0, 0);
            }
        }
        #pragma unroll
        for (int jt = 0; jt < 3; ++jt)
            #pragma unroll
            for (int rr = 0; rr < 4; ++rr) {
                int oc = w * 48 + jt * 16 + l4 * 4 + rr;
                float pb = Pb[oc];
                float* obase = out + (size_t)(b * 192 + oc) * 16384;
                #pragma unroll
                for (int nt = 0; nt < 4; ++nt) {
                    int tok = nt * 16 + l15;
                    obase[(y0 + (tok >> 3)) * 128 + x0 + (tok & 7)] = acc[jt][nt][rr] + pb;
                }
            }
    }
}

extern "C" void kernel_launch(void* const* d_in, const int* in_sizes, int n_in,
                              void* d_out, int out_size, void* d_ws, size_t ws_size,
                              hipStream_t stream) {
    const float* x   = (const float*)d_in[0];
    const float* Vw  = (const float*)d_in[1];
    const float* Vb  = (const float*)d_in[2];
    const float* QKw = (const float*)d_in[3];
    const float* QKb = (const float*)d_in[4];
    const float* Pw  = (const float*)d_in[5];
    const float* Pb  = (const float*)d_in[6];
    const float* Mw1 = (const float*)d_in[7];
    const float* Mb1 = (const float*)d_in[8];
    const float* Mw2 = (const float*)d_in[9];
    const float* Mb2 = (const float*)d_in[10];
    float* outp  = (float*)d_out;
    float* biasw = (float*)d_ws;           // 5400 B bias table

    bias_table_kernel<<<dim3(4), dim3(64), 0, stream>>>(Mw1, Mb1, Mw2, Mb2, biasw);

    (void)hipFuncSetAttribute((const void*)fused_win_attn,
                              hipFuncAttributeMaxDynamicSharedMemorySize, LDS_BYTES);
    fused_win_attn<<<dim3(2048), dim3(256), LDS_BYTES, stream>>>(
        x, Vw, Vb, QKw, QKb, Pw, Pb, biasw, outp);
}

// Round 4
// 381.161 us; speedup vs baseline: 4.7514x; 1.4225x over previous
//
#include <hip/hip_runtime.h>

// B=8, C=192, H=W=128, NH=6, HD=32, WS=8, N=64 tokens/window. 2048 windows.
// Round 4: 512 threads (8 waves) per block for 2 waves/SIMD TLP; bf16 weights
// precomputed once into d_ws (was: every block re-fetched+converted f32 weights).
#define SCALEQ 0.17677669529663687f   // 32^-0.5

typedef __bf16 bf16x8 __attribute__((ext_vector_type(8)));
typedef float f32x4 __attribute__((ext_vector_type(4)));

__device__ __forceinline__ float bflo(unsigned int u) { return __uint_as_float(u << 16); }
__device__ __forceinline__ float bfhi(unsigned int u) { return __uint_as_float(u & 0xffff0000u); }
__device__ __forceinline__ unsigned short f2b(float f) {
    unsigned int u = __float_as_uint(f);
    u += 0x7fffu + ((u >> 16) & 1u);      // RNE
    return (unsigned short)(u >> 16);
}

// LDS map (swizzle: byte ^= (row&7)<<4; strides: 384B for [64][192], 128B for [*][64])
//  BUF0   0      xs[64][192] (P1-P2) | o[64][192] (P3-P4) | y[64][192] (P5-P6)
//  QOFF   24576  q[64][192] (P2-P3)  | P: 6 heads x [64][64] bf16, 8KB/head (P4-P5)
//  KOFF   49152  k[64][192] (P2-P3)  | (P heads 3..5)
//  VOFF   73728  v_n[64][192] (P2-P4)
//  VTOFF  98304  v_t[192][64] (P2-P5)
//  BTOFF  122880 bias table 225*6 f32 (5400B)
#define BUF0   0
#define QOFF   24576
#define KOFF   49152
#define POFF   24576
#define VOFF   73728
#define VTOFF  98304
#define BTOFF  122880
#define LDS_BYTES 128280

// d_ws layout (bytes): [0] qkv weights bf16 [576][192] | [221184] proj bf16 [192][192]
//                      | [294912] bias table 225*6 f32
#define WS_WQKV_ELEMS 110592
#define WS_WP_OFF_EL  110592
#define WS_BT_OFF_B   294912

__device__ __forceinline__ bf16x8 ldsf(const char* p) {
    uint4 u = *(const uint4*)p;
    return __builtin_bit_cast(bf16x8, u);
}
__device__ __forceinline__ bf16x8 gldf(const unsigned short* p) {
    uint4 u = *(const uint4*)p;
    return __builtin_bit_cast(bf16x8, u);
}

// ---- prep kernel 1: weights f32 -> bf16 into d_ws (runs once per launch) ----
__global__ void wprep_kernel(const float* __restrict__ QKw, const float* __restrict__ Vw,
                             const float* __restrict__ Pw, unsigned short* __restrict__ wsb) {
    int i = blockIdx.x * 256 + threadIdx.x;        // 0 .. 147455
    if (i >= 147456) return;
    if (i < WS_WQKV_ELEMS) {                       // qkv: row r (0..575), col c
        int r = i / 192, c = i - r * 192;
        float v = (r < 384) ? QKw[r * 192 + c] : Vw[(r - 384) * 192 + c];
        wsb[i] = f2b(v);
    } else {
        int j = i - WS_WQKV_ELEMS;                 // proj flat
        wsb[WS_WP_OFF_EL + j] = f2b(Pw[j]);
    }
}

// ---- prep kernel 2: rel-pos bias MLP table (225 x 6) ----
__global__ void bias_table_kernel(const float* __restrict__ Mw1, const float* __restrict__ Mb1,
                                  const float* __restrict__ Mw2, const float* __restrict__ Mb2,
                                  float* __restrict__ bias_out) {
    int t = blockIdx.x * 64 + threadIdx.x;
    if (t >= 225) return;
    int dyi = t / 15, dxi = t % 15;
    float dy = (float)(dyi - 7), dx = (float)(dxi - 7);
    float f0 = copysignf(log1pf(fabsf(dy)), dy);
    float f1 = copysignf(log1pf(fabsf(dx)), dx);
    float a0 = Mb2[0], a1 = Mb2[1], a2 = Mb2[2], a3 = Mb2[3], a4 = Mb2[4], a5 = Mb2[5];
    for (int u = 0; u < 256; ++u) {
        float hv = fmaxf(f0 * Mw1[u] + f1 * Mw1[256 + u] + Mb1[u], 0.0f);
        const float* w2 = Mw2 + u * 6;
        a0 = fmaf(hv, w2[0], a0); a1 = fmaf(hv, w2[1], a1);
        a2 = fmaf(hv, w2[2], a2); a3 = fmaf(hv, w2[3], a3);
        a4 = fmaf(hv, w2[4], a4); a5 = fmaf(hv, w2[5], a5);
    }
    float* bt = bias_out + t * 6;
    bt[0] = a0; bt[1] = a1; bt[2] = a2; bt[3] = a3; bt[4] = a4; bt[5] = a5;
}

__global__ __launch_bounds__(512)
void fused_win_attn(const float* __restrict__ x,
                    const float* __restrict__ Vb, const float* __restrict__ QKb,
                    const float* __restrict__ Pb,
                    const unsigned short* __restrict__ wqkv,   // bf16 [576][192]
                    const unsigned short* __restrict__ wp,     // bf16 [192][192]
                    const float* __restrict__ bias_g,
                    float* __restrict__ out)
{
    extern __shared__ char smem[];
    const int t   = threadIdx.x;
    const int wv  = t >> 6;           // wave 0..7
    const int l15 = t & 15;
    const int l4  = (t >> 4) & 3;     // (lane>>4) within wave

    const int wid = blockIdx.x;
    const int b   = wid >> 8;
    const int wy  = (wid >> 4) & 15;
    const int wx  = wid & 15;
    const int y0  = wy * 8, x0 = wx * 8;

    const f32x4 zz = {0.0f, 0.0f, 0.0f, 0.0f};

    // ---- P0: bias table global -> LDS ----
    {
        float* bt = (float*)(smem + BTOFF);
        for (int i = t; i < 1350; i += 512) bt[i] = bias_g[i];
    }

    // ---- P1: load x window -> xs[tok][ch] bf16 swizzled (3072 float4 / 512 thr) ----
    {
        const float* xb = x + (size_t)b * 192 * 16384;
        #pragma unroll
        for (int i = 0; i < 6; ++i) {
            int idx = t + 512 * i;
            int c = idx >> 4, sub = idx & 15;
            int r = sub >> 1, hf = sub & 1;
            float4 v4 = *(const float4*)(xb + c * 16384 + (y0 + r) * 128 + x0 + hf * 4);
            int n0 = r * 8 + hf * 4;
            unsigned short sv[4] = {f2b(v4.x), f2b(v4.y), f2b(v4.z), f2b(v4.w)};
            #pragma unroll
            for (int e = 0; e < 4; ++e) {
                int n = n0 + e;
                *(unsigned short*)(smem + BUF0 + ((n * 384 + c * 2) ^ ((n & 7) << 4))) = sv[e];
            }
        }
    }
    __syncthreads();

    // ---- P2: qkv GEMM via MFMA. wave (wcol,wrow): cols [144*wcol,+144), toks [32*wrow,+32) ----
    {
        const int wcol = wv & 3, wrow = wv >> 2;
        // hoist A fragments: 12 x bf16x8 (48 VGPR), reused across the 3 col-chunks
        bf16x8 afr[6][2];
        #pragma unroll
        for (int ks = 0; ks < 6; ++ks)
            #pragma unroll
            for (int mtl = 0; mtl < 2; ++mtl) {
                int row = (wrow * 2 + mtl) * 16 + l15;
                afr[ks][mtl] = ldsf(smem + BUF0 + ((row * 384 + ks * 64 + l4 * 16) ^ ((row & 7) << 4)));
            }
        #pragma unroll
        for (int chunk = 0; chunk < 3; ++chunk) {
            f32x4 acc[3][2];
            #pragma unroll
            for (int j = 0; j < 3; ++j) { acc[j][0] = zz; acc[j][1] = zz; }
            #pragma unroll
            for (int ks = 0; ks < 6; ++ks) {
                bf16x8 bfr[3];
                #pragma unroll
                for (int j = 0; j < 3; ++j) {
                    int ob = wcol * 144 + chunk * 48 + j * 16;
                    bfr[j] = gldf(wqkv + (size_t)(ob + l15) * 192 + ks * 32 + l4 * 8);
                }
                #pragma unroll
                for (int j = 0; j < 3; ++j)
                    #pragma unroll
                    for (int mtl = 0; mtl < 2; ++mtl)
                        acc[j][mtl] = __builtin_amdgcn_mfma_f32_16x16x32_bf16(afr[ks][mtl], bfr[j], acc[j][mtl], 0, 0, 0);
            }
            // epilogue: +bias, scale q, write q/k/v (v also transposed)
            #pragma unroll
            for (int j = 0; j < 3; ++j) {
                int ob  = wcol * 144 + chunk * 48 + j * 16;
                int och = ob + l15;
                float bv = (ob < 384) ? QKb[och] : Vb[och - 384];
                #pragma unroll
                for (int mtl = 0; mtl < 2; ++mtl) {
                    #pragma unroll
                    for (int rr = 0; rr < 4; ++rr) {
                        float val = acc[j][mtl][rr] + bv;
                        int tok = (wrow * 2 + mtl) * 16 + l4 * 4 + rr;
                        if (ob < 192) {
                            *(unsigned short*)(smem + QOFF + ((tok * 384 + och * 2) ^ ((tok & 7) << 4))) = f2b(val * SCALEQ);
                        } else if (ob < 384) {
                            int ch = och - 192;
                            *(unsigned short*)(smem + KOFF + ((tok * 384 + ch * 2) ^ ((tok & 7) << 4))) = f2b(val);
                        } else {
                            int ch = och - 384;
                            unsigned short hv = f2b(val);
                            *(unsigned short*)(smem + VOFF  + ((tok * 384 + ch * 2) ^ ((tok & 7) << 4))) = hv;
                            *(unsigned short*)(smem + VTOFF + ((ch * 128 + tok * 2) ^ ((ch & 7) << 4))) = hv;
                        }
                    }
                }
            }
        }
    }
    __syncthreads();

    // ---- P3: 8x8 circular conv, register-blocked. 384 threads: (rn 0..7, 48 x 4ch) ----
    if (t < 384) {
        const int rn = t / 48, cc = t % 48;
        const int c0b = cc * 8;               // byte offset of 4-ch chunk (covers 192 ch)
        float acc[8][4];
        #pragma unroll
        for (int cn = 0; cn < 8; ++cn)
            #pragma unroll
            for (int c = 0; c < 4; ++c) acc[cn][c] = 0.0f;

        #pragma unroll
        for (int kh = 0; kh < 2; ++kh) {
            unsigned int klo[32], khi[32];
            #pragma unroll
            for (int m = 0; m < 32; ++m) {
                int row = kh * 32 + m;
                uint2 kv = *(const uint2*)(smem + KOFF + ((row * 384 + c0b) ^ ((row & 7) << 4)));
                klo[m] = kv.x; khi[m] = kv.y;
            }
            #pragma unroll
            for (int mrl = 0; mrl < 4; ++mrl) {
                const int mr = kh * 4 + mrl;
                float kf[8][4];
                #pragma unroll
                for (int mc = 0; mc < 8; ++mc) {
                    int m = mrl * 8 + mc;
                    kf[mc][0] = bflo(klo[m]); kf[mc][1] = bfhi(klo[m]);
                    kf[mc][2] = bflo(khi[m]); kf[mc][3] = bfhi(khi[m]);
                }
                const int npr = (rn - mr) & 7;
                #pragma unroll
                for (int npc = 0; npc < 8; ++npc) {
                    int np = npr * 8 + npc;
                    uint2 qv = *(const uint2*)(smem + QOFF + ((np * 384 + c0b) ^ ((np & 7) << 4)));
                    float qf[4] = {bflo(qv.x), bfhi(qv.x), bflo(qv.y), bfhi(qv.y)};
                    #pragma unroll
                    for (int mc = 0; mc < 8; ++mc) {
                        int cn = (npc + mc) & 7;
                        acc[cn][0] = fmaf(qf[0], kf[mc][0], acc[cn][0]);
                        acc[cn][1] = fmaf(qf[1], kf[mc][1], acc[cn][1]);
                        acc[cn][2] = fmaf(qf[2], kf[mc][2], acc[cn][2]);
                        acc[cn][3] = fmaf(qf[3], kf[mc][3], acc[cn][3]);
                    }
                }
            }
        }
        #pragma unroll
        for (int cn = 0; cn < 8; ++cn) {
            int n = rn * 8 + cn;
            uint2 pk;
            pk.x = (unsigned int)f2b(acc[cn][0]) | ((unsigned int)f2b(acc[cn][1]) << 16);
            pk.y = (unsigned int)f2b(acc[cn][2]) | ((unsigned int)f2b(acc[cn][3]) << 16);
            *(uint2*)(smem + BUF0 + ((n * 384 + c0b) ^ ((n & 7) << 4))) = pk;
        }
    }
    __syncthreads();

    // ---- P4: S = o.v^T + bias, softmax, P -> LDS. 24 units (h, mt), 3 per wave ----
    {
        const float* bt = (const float*)(smem + BTOFF);
        for (int i = 0; i < 3; ++i) {
            int u = wv * 3 + i;
            int h = u >> 2, mt = u & 3;
            int arow = mt * 16 + l15;
            bf16x8 afr = ldsf(smem + BUF0 + ((arow * 384 + h * 64 + l4 * 16) ^ ((arow & 7) << 4)));
            f32x4 acc[4];
            #pragma unroll
            for (int nt = 0; nt < 4; ++nt) {
                int brow = nt * 16 + l15;
                bf16x8 bfr = ldsf(smem + VOFF + ((brow * 384 + h * 64 + l4 * 16) ^ ((brow & 7) << 4)));
                acc[nt] = __builtin_amdgcn_mfma_f32_16x16x32_bf16(afr, bfr, zz, 0, 0, 0);
            }
            float s[4][4];
            #pragma unroll
            for (int nt = 0; nt < 4; ++nt) {
                int m = nt * 16 + l15;
                int myr = m >> 3, myc = m & 7;
                #pragma unroll
                for (int rr = 0; rr < 4; ++rr) {
                    int n = mt * 16 + l4 * 4 + rr;
                    int dy = (n >> 3) - myr + 7, dx = (n & 7) - myc + 7;
                    s[nt][rr] = acc[nt][rr] + bt[(dy * 15 + dx) * 6 + h];
                }
            }
            float inv[4];
            #pragma unroll
            for (int rr = 0; rr < 4; ++rr) {
                float m0 = fmaxf(fmaxf(s[0][rr], s[1][rr]), fmaxf(s[2][rr], s[3][rr]));
                m0 = fmaxf(m0, __shfl_xor(m0, 1));
                m0 = fmaxf(m0, __shfl_xor(m0, 2));
                m0 = fmaxf(m0, __shfl_xor(m0, 4));
                m0 = fmaxf(m0, __shfl_xor(m0, 8));
                float sm = 0.0f;
                #pragma unroll
                for (int nt = 0; nt < 4; ++nt) {
                    float p = __expf(s[nt][rr] - m0);
                    s[nt][rr] = p; sm += p;
                }
                sm += __shfl_xor(sm, 1); sm += __shfl_xor(sm, 2);
                sm += __shfl_xor(sm, 4); sm += __shfl_xor(sm, 8);
                inv[rr] = 1.0f / sm;
            }
            #pragma unroll
            for (int nt = 0; nt < 4; ++nt)
                #pragma unroll
                for (int rr = 0; rr < 4; ++rr) {
                    int n = mt * 16 + l4 * 4 + rr, m = nt * 16 + l15;
                    *(unsigned short*)(smem + POFF + h * 8192 + ((n * 128 + m * 2) ^ ((n & 7) << 4)))
                        = f2b(s[nt][rr] * inv[rr]);
                }
        }
    }
    __syncthreads();

    // ---- P5: Y = P.v  (3 units per wave) -> y[tok][ch] in BUF0 ----
    {
        for (int i = 0; i < 3; ++i) {
            int u = wv * 3 + i;
            int h = u >> 2, mt = u & 3;
            bf16x8 pa[2];
            #pragma unroll
            for (int ks = 0; ks < 2; ++ks) {
                int row = mt * 16 + l15;
                pa[ks] = ldsf(smem + POFF + h * 8192 + ((row * 128 + ks * 64 + l4 * 16) ^ ((row & 7) << 4)));
            }
            f32x4 acc[2];
            acc[0] = zz; acc[1] = zz;
            #pragma unroll
            for (int dt = 0; dt < 2; ++dt)
                #pragma unroll
                for (int ks = 0; ks < 2; ++ks) {
                    int ch = h * 32 + dt * 16 + l15;
                    bf16x8 bfr = ldsf(smem + VTOFF + ((ch * 128 + ks * 64 + l4 * 16) ^ ((ch & 7) << 4)));
                    acc[dt] = __builtin_amdgcn_mfma_f32_16x16x32_bf16(pa[ks], bfr, acc[dt], 0, 0, 0);
                }
            #pragma unroll
            for (int dt = 0; dt < 2; ++dt)
                #pragma unroll
                for (int rr = 0; rr < 4; ++rr) {
                    int tok = mt * 16 + l4 * 4 + rr;
                    int ch  = h * 32 + dt * 16 + l15;
                    *(unsigned short*)(smem + BUF0 + ((tok * 384 + ch * 2) ^ ((tok & 7) << 4))) = f2b(acc[dt][rr]);
                }
        }
    }
    __syncthreads();

    // ---- P6: proj, transposed: OUTt[oc][tok] = Pw . y^T. wave (wc,wr): oc [48wc,+48), toks [32wr,+32) ----
    {
        const int wc = wv & 3, wr = wv >> 2;
        f32x4 acc[3][2];
        #pragma unroll
        for (int jt = 0; jt < 3; ++jt) { acc[jt][0] = zz; acc[jt][1] = zz; }

        #pragma unroll
        for (int ks = 0; ks < 6; ++ks) {
            bf16x8 bfr[2];
            #pragma unroll
            for (int ntl = 0; ntl < 2; ++ntl) {
                int tok = (wr * 2 + ntl) * 16 + l15;
                bfr[ntl] = ldsf(smem + BUF0 + ((tok * 384 + ks * 64 + l4 * 16) ^ ((tok & 7) << 4)));
            }
            #pragma unroll
            for (int jt = 0; jt < 3; ++jt) {
                int oc = wc * 48 + jt * 16;
                bf16x8 afr = gldf(wp + (size_t)(oc + l15) * 192 + ks * 32 + l4 * 8);
                #pragma unroll
                for (int ntl = 0; ntl < 2; ++ntl)
                    acc[jt][ntl] = __builtin_amdgcn_mfma_f32_16x16x32_bf16(afr, bfr[ntl], acc[jt][ntl], 0, 0, 0);
            }
        }
        #pragma unroll
        for (int jt = 0; jt < 3; ++jt)
            #pragma unroll
            for (int rr = 0; rr < 4; ++rr) {
                int oc = wc * 48 + jt * 16 + l4 * 4 + rr;
                float pb = Pb[oc];
                float* obase = out + (size_t)(b * 192 + oc) * 16384;
                #pragma unroll
                for (int ntl = 0; ntl < 2; ++ntl) {
                    int tok = (wr * 2 + ntl) * 16 + l15;
                    obase[(y0 + (tok >> 3)) * 128 + x0 + (tok & 7)] = acc[jt][ntl][rr] + pb;
                }
            }
    }
}

extern "C" void kernel_launch(void* const* d_in, const int* in_sizes, int n_in,
                              void* d_out, int out_size, void* d_ws, size_t ws_size,
                              hipStream_t stream) {
    const float* x   = (const float*)d_in[0];
    const float* Vw  = (const float*)d_in[1];
    const float* Vb  = (const float*)d_in[2];
    const float* QKw = (const float*)d_in[3];
    const float* QKb = (const float*)d_in[4];
    const float* Pw  = (const float*)d_in[5];
    const float* Pb  = (const float*)d_in[6];
    const float* Mw1 = (const float*)d_in[7];
    const float* Mb1 = (const float*)d_in[8];
    const float* Mw2 = (const float*)d_in[9];
    const float* Mb2 = (const float*)d_in[10];
    float* outp = (float*)d_out;

    unsigned short* wsb  = (unsigned short*)d_ws;              // bf16 weights
    float* biasw = (float*)((char*)d_ws + WS_BT_OFF_B);        // bias table

    wprep_kernel<<<dim3(576), dim3(256), 0, stream>>>(QKw, Vw, Pw, wsb);
    bias_table_kernel<<<dim3(4), dim3(64), 0, stream>>>(Mw1, Mb1, Mw2, Mb2, biasw);

    (void)hipFuncSetAttribute((const void*)fused_win_attn,
                              hipFuncAttributeMaxDynamicSharedMemorySize, LDS_BYTES);
    fused_win_attn<<<dim3(2048), dim3(512), LDS_BYTES, stream>>>(
        x, Vb, QKb, Pb, wsb, wsb + WS_WP_OFF_EL, biasw, outp);
}